// Round 2
// baseline (266.289 us; speedup 1.0000x reference)
//
#include <hip/hip_runtime.h>
#include <hip/hip_bf16.h>

// BLSTM: B=1024, T=512, V=128, H=128, HH=64, gates=256/dir.
// R18: dual-recurrence interleave. Each block (256 thr, 4 waves, 1/CU) owns
// 8 batch rows of ONE dir, split into two independent row-groups G0/G1.
// Every lane advances BOTH recurrences each step -> G1's MFMA/trans fills
// G0's LDS-roundtrip + transcendental latency IN-STREAM (R17 relied on two
// co-resident blocks anti-phasing; measured step was 1.8x the chain).
// Shared W_hh B-frags between groups (same dir). One barrier serves 2 h/lane.
// x-offsets staged dir-REVERSED (loop always ascends; no per-step selects),
// read as int4 once per 4 steps with mov-free register rotation.
// hbuf pitch 80 u16 (stride = 8 mod 32 dwords): A-reads/h-writes <=2-way
// bank aliasing (free) vs pitch-72's 4-way.
// Math is bit-identical to R17 (same MFMA order, z4 C-in, x-add, f2bf_rne):
// absmax oracle must stay EXACTLY 9.766e-4.

#define T_STEPS 512
#define BATCH   1024
#define VOCAB   128
#define HID     128
#define HH      64
#define NG      256
#define XPITCH  520    // 512 steps + 8 guard elems (zeros) at the high end

#define L2E  1.4426950408889634f
#define L2E2 2.8853900817779268f

typedef __attribute__((ext_vector_type(8))) short bf16x8;
typedef __attribute__((ext_vector_type(4))) float f32x4;
typedef unsigned int  u32;
typedef unsigned short u16;

__device__ __forceinline__ float sigmoid_f(float x) {
    return __builtin_amdgcn_rcpf(1.0f + __builtin_amdgcn_exp2f(-x * L2E));
}
__device__ __forceinline__ float tanh_f(float x) {
    return 1.0f - 2.0f * __builtin_amdgcn_rcpf(1.0f + __builtin_amdgcn_exp2f(x * L2E2));
}
__device__ __forceinline__ u16 f2bf_rne(float f) {
    u32 u = __builtin_bit_cast(u32, f);
    u += 0x7FFFu + ((u >> 16) & 1u);
    return (u16)(u >> 16);
}
// barrier with LDS-only drain: global (tab) prefetch loads are NOT drained —
// their vmcnt wait lands at the use point next step.
__device__ __forceinline__ void barrier_lgkm() {
    asm volatile("s_waitcnt lgkmcnt(0)\n\ts_barrier" ::: "memory");
}

// ---------------- Kernel 1: tab build + W_hh bf16 convert (fused) ----------
// tab3 layout: [d][v][j][4] = dot(emb[v], W_ih_d[g*64+j]) for g=i,f,g,o.
__global__ __launch_bounds__(256) void build_tab_kernel(
    const float* __restrict__ emb,
    const float* __restrict__ W_ih_f,
    const float* __restrict__ W_ih_b,
    const float* __restrict__ W_hh_f,
    const float* __restrict__ W_hh_b,
    float* __restrict__ tab3,
    u16*   __restrict__ whh_bf)
{
    int v = blockIdx.x, d = blockIdx.y, tid = threadIdx.x;
    int j = tid >> 2, g = tid & 3;
    int gr = g * HH + j;                      // W_ih gate row
    const float* W = d ? W_ih_b : W_ih_f;
    const float4* e4 = (const float4*)(emb + v * HID);
    const float4* w4 = (const float4*)(W + gr * HID);
    float acc = 0.0f;
#pragma unroll
    for (int k = 0; k < HID / 4; ++k) {
        float4 e = e4[k]; float4 w = w4[k];
        acc += e.x * w.x + e.y * w.y + e.z * w.z + e.w * w.w;
    }
    tab3[(d * VOCAB + v) * NG + j * 4 + g] = acc;

    // fused W_hh convert: plain row-major [2][256][64]
    if (tid < 128) {
        const float* Whh = d ? W_hh_b : W_hh_f;
        int idx = v * 128 + tid;              // 0..16383 within this dir
        whh_bf[d * NG * HH + idx] = f2bf_rne(Whh[idx]);
    }
}

// ---------------- Kernel 2: MFMA recurrence ----------------
// grid (128,2), block 256 (4 waves), 1 block/CU.
__global__ __launch_bounds__(256, 1) void lstm_rec_kernel(
    const int*  __restrict__ x,        // [1024][512]
    const u16*  __restrict__ whh_bf,   // [2][256][64] bf16 bits
    const float* __restrict__ tab3,    // [2][128][64][4] floats
    float* __restrict__ hfin)          // [2][1024][64]
{
    __shared__ u32 xsT[8][XPITCH];                   // dir-reversed, 16640 B
    __shared__ __align__(16) u16 hbuf[2][2][4][80];  // [grp][pp][row][80], 2560 B

    const int tid  = threadIdx.x;
    const int lane = tid & 63;
    const int wave = tid >> 6;           // 0..3
    const int quad = lane >> 4;          // 0..3  == my row within group
    const int m    = lane & 15;          // my j within wave's 16
    const int dir    = blockIdx.y;
    const int b_base = blockIdx.x * 8;

    // stage x pre-scaled to tab3 byte offset (v<<10), dir-REVERSED so the
    // main loop always walks t ascending for both directions.
    for (int i = tid; i < 8 * T_STEPS; i += 256) {
        int bl = i >> 9, t = i & (T_STEPS - 1);
        int ts = dir ? (T_STEPS - 1 - t) : t;
        xsT[bl][ts] = ((u32)x[(b_base + bl) * T_STEPS + t]) << 10;
    }
    if (tid < 64)                         // zero high guard [512..519] x 8 rows
        xsT[tid >> 3][T_STEPS + (tid & 7)] = 0;
    for (int i = tid; i < (int)(sizeof(hbuf) / 4); i += 256)
        ((u32*)hbuf)[i] = 0;

    // persistent B-fragments, SHARED by both groups (same dir):
    // tile g = gate g, col m -> gate row g*64+wave*16+m
    const u16* WB = whh_bf + dir * NG * HH;
    bf16x8 Bg[4][2];
#pragma unroll
    for (int g = 0; g < 4; ++g)
#pragma unroll
        for (int kc = 0; kc < 2; ++kc)
            Bg[g][kc] = *(const bf16x8*)(WB + (g * HH + wave * 16 + m) * HH
                                            + kc * 32 + quad * 8);

    const char* tabB = (const char*)tab3 + (size_t)dir * VOCAB * NG * 4;
    const u32 joff = (u32)(wave * 16 + m) * 16u;     // j*16 bytes
    const int aoff = (m >> 2) * 80 + quad * 8;       // A-frag read (u16 units)
    const int woff = quad * 80 + wave * 16 + m;      // h write  (u16 units)

    const f32x4 z4 = {0.f, 0.f, 0.f, 0.f};           // loop-invariant C-in
    float cc0 = 0.f, h0 = 0.f;                       // G0 state
    float cc1 = 0.f, h1 = 0.f;                       // G1 state

    __syncthreads();   // xsT + hbuf init visible

    // x-offset quad registers: qGA covers steps 8k..8k+3 (elems .x..w),
    // qGB covers 8k+4..8k+7. Rotation is mov-free: reloads land in the
    // register whose elems are already consumed.
    int4 q0A = *(const int4*)&xsT[quad][0];
    int4 q0B = *(const int4*)&xsT[quad][4];
    int4 q1A = *(const int4*)&xsT[4 + quad][0];
    int4 q1B = *(const int4*)&xsT[4 + quad][4];

    // x-term double buffers (XA = even steps, XB = odd), per group
    float4 XA0 = *(const float4*)(tabB + (u32)q0A.x + joff);
    float4 XA1 = *(const float4*)(tabB + (u32)q1A.x + joff);
    float4 XB0, XB1;

    auto stepf = [&](int p, const float4 Xc0, const float4 Xc1,
                     float4& Xn0, float4& Xn1, u32 e0, u32 e1) {
        const u16* r0 = &hbuf[0][p][0][0];
        const u16* r1 = &hbuf[1][p][0][0];
        u16* w0 = &hbuf[0][p ^ 1][0][0];
        u16* w1 = &hbuf[1][p ^ 1][0][0];
        bf16x8 A00 = *(const bf16x8*)(r0 + aoff);         // G0 k 0..31
        bf16x8 A01 = *(const bf16x8*)(r0 + aoff + 32);    // G0 k 32..63
        bf16x8 A10 = *(const bf16x8*)(r1 + aoff);         // G1
        bf16x8 A11 = *(const bf16x8*)(r1 + aoff + 32);

        // issue x-term loads for next step (vmcnt wait lands at next use)
        Xn0 = *(const float4*)(tabB + e0 + joff);
        Xn1 = *(const float4*)(tabB + e1 + joff);

        // ---- G0: 4 gate chains, K=64; acc[0..3] all equal gates[quad][j]
        f32x4 aI = __builtin_amdgcn_mfma_f32_16x16x32_bf16(A00, Bg[0][0], z4, 0, 0, 0);
        f32x4 aF = __builtin_amdgcn_mfma_f32_16x16x32_bf16(A00, Bg[1][0], z4, 0, 0, 0);
        f32x4 aG = __builtin_amdgcn_mfma_f32_16x16x32_bf16(A00, Bg[2][0], z4, 0, 0, 0);
        f32x4 aO = __builtin_amdgcn_mfma_f32_16x16x32_bf16(A00, Bg[3][0], z4, 0, 0, 0);
        aI = __builtin_amdgcn_mfma_f32_16x16x32_bf16(A01, Bg[0][1], aI, 0, 0, 0);
        aF = __builtin_amdgcn_mfma_f32_16x16x32_bf16(A01, Bg[1][1], aF, 0, 0, 0);
        aG = __builtin_amdgcn_mfma_f32_16x16x32_bf16(A01, Bg[2][1], aG, 0, 0, 0);
        aO = __builtin_amdgcn_mfma_f32_16x16x32_bf16(A01, Bg[3][1], aO, 0, 0, 0);

        float gi0 = aI[0] + Xc0.x;
        float gf0 = aF[0] + Xc0.y;
        float gg0 = aG[0] + Xc0.z;
        float go0 = aO[0] + Xc0.w;

        // ---- G1 (same B-frags)
        f32x4 bI = __builtin_amdgcn_mfma_f32_16x16x32_bf16(A10, Bg[0][0], z4, 0, 0, 0);
        f32x4 bF = __builtin_amdgcn_mfma_f32_16x16x32_bf16(A10, Bg[1][0], z4, 0, 0, 0);
        f32x4 bG = __builtin_amdgcn_mfma_f32_16x16x32_bf16(A10, Bg[2][0], z4, 0, 0, 0);
        f32x4 bO = __builtin_amdgcn_mfma_f32_16x16x32_bf16(A10, Bg[3][0], z4, 0, 0, 0);
        bI = __builtin_amdgcn_mfma_f32_16x16x32_bf16(A11, Bg[0][1], bI, 0, 0, 0);
        bF = __builtin_amdgcn_mfma_f32_16x16x32_bf16(A11, Bg[1][1], bF, 0, 0, 0);
        bG = __builtin_amdgcn_mfma_f32_16x16x32_bf16(A11, Bg[2][1], bG, 0, 0, 0);
        bO = __builtin_amdgcn_mfma_f32_16x16x32_bf16(A11, Bg[3][1], bO, 0, 0, 0);

        float gi1 = bI[0] + Xc1.x;
        float gf1 = bF[0] + Xc1.y;
        float gg1 = bG[0] + Xc1.z;
        float go1 = bO[0] + Xc1.w;

        // two independent nonlinear chains — compiler interleaves, G1 hides
        // under G0's trans latency and vice versa
        cc0 = sigmoid_f(gf0) * cc0 + sigmoid_f(gi0) * tanh_f(gg0);
        h0  = sigmoid_f(go0) * tanh_f(cc0);
        cc1 = sigmoid_f(gf1) * cc1 + sigmoid_f(gi1) * tanh_f(gg1);
        h1  = sigmoid_f(go1) * tanh_f(cc1);

        w0[woff] = f2bf_rne(h0);
        w1[woff] = f2bf_rne(h1);

        barrier_lgkm();
    };

    for (int kk = 0; kk < T_STEPS / 8; ++kk) {
        // steps 8kk .. 8kk+3 (prefetch elems .y.z.w of A-quads, then B.x)
        stepf(0, XA0, XA1, XB0, XB1, (u32)q0A.y, (u32)q1A.y);
        stepf(1, XB0, XB1, XA0, XA1, (u32)q0A.z, (u32)q1A.z);
        stepf(0, XA0, XA1, XB0, XB1, (u32)q0A.w, (u32)q1A.w);
        q0A = *(const int4*)&xsT[quad][8 * kk + 8];       // steps 8kk+8..11
        q1A = *(const int4*)&xsT[4 + quad][8 * kk + 8];
        stepf(1, XB0, XB1, XA0, XA1, (u32)q0B.x, (u32)q1B.x);
        // steps 8kk+4 .. 8kk+7
        stepf(0, XA0, XA1, XB0, XB1, (u32)q0B.y, (u32)q1B.y);
        stepf(1, XB0, XB1, XA0, XA1, (u32)q0B.z, (u32)q1B.z);
        stepf(0, XA0, XA1, XB0, XB1, (u32)q0B.w, (u32)q1B.w);
        q0B = *(const int4*)&xsT[quad][8 * kk + 12];      // steps 8kk+12..15
        q1B = *(const int4*)&xsT[4 + quad][8 * kk + 12];
        stepf(1, XB0, XB1, XA0, XA1, (u32)q0A.x, (u32)q1A.x);
    }

    // every lane owns (b_base+quad, j) for G0 and (b_base+4+quad, j) for G1
    {
        int j = wave * 16 + m;
        hfin[(dir * BATCH + b_base + quad) * HH + j]     = h0;
        hfin[(dir * BATCH + b_base + 4 + quad) * HH + j] = h1;
    }
}

// ---------------- Kernel 3: final FC (W_fc in LDS, 8 rows/block) ----------
__global__ __launch_bounds__(256) void fc_kernel(
    const float* __restrict__ hfin,    // [2][1024][64]
    const float* __restrict__ W_fc,    // [128][128]
    const float* __restrict__ b_fc,    // [128]
    float* __restrict__ out)           // [1024][128]
{
    __shared__ float wfc[HID * 129];   // row-padded: bank stride 129
    __shared__ float hid[8][HID];
    const int tid = threadIdx.x;
    const int b0  = blockIdx.x * 8;

    for (int i = tid; i < HID * HID; i += 256) {
        int r = i >> 7, c = i & 127;
        wfc[r * 129 + c] = W_fc[i];
    }
    for (int i = tid; i < 8 * HID; i += 256) {
        int bb = i >> 7, v = i & 127;
        hid[bb][v] = (v < HH) ? hfin[(0 * BATCH + b0 + bb) * HH + v]
                              : hfin[(1 * BATCH + b0 + bb) * HH + (v - HH)];
    }
    __syncthreads();

    const int v  = tid & 127;
    const int bs = (tid >> 7) * 4;     // rows [bs, bs+4)
    const float bias = b_fc[v];
    const float* wrow = wfc + v * 129;
#pragma unroll
    for (int r = 0; r < 4; ++r) {
        const float* h = hid[bs + r];
        float acc = bias;
#pragma unroll
        for (int k = 0; k < HID; k += 4) {
            acc += wrow[k]     * h[k]     + wrow[k + 1] * h[k + 1]
                 + wrow[k + 2] * h[k + 2] + wrow[k + 3] * h[k + 3];
        }
        out[(b0 + bs + r) * HID + v] = acc;
    }
}

extern "C" void kernel_launch(void* const* d_in, const int* in_sizes, int n_in,
                              void* d_out, int out_size, void* d_ws, size_t ws_size,
                              hipStream_t stream) {
    const int*   x      = (const int*)d_in[0];
    // d_in[1] = lengths : unused by the reference
    const float* emb    = (const float*)d_in[2];
    const float* W_ih_f = (const float*)d_in[3];
    const float* W_hh_f = (const float*)d_in[4];
    const float* W_ih_b = (const float*)d_in[5];
    const float* W_hh_b = (const float*)d_in[6];
    const float* W_fc   = (const float*)d_in[7];
    const float* b_fc   = (const float*)d_in[8];
    float* out = (float*)d_out;

    float* tab3   = (float*)d_ws;                         // 65536 f32
    u16*   whh_bf = (u16*)(tab3 + 2 * VOCAB * NG);        // 32768 u16
    float* hfin   = (float*)(whh_bf + 2 * NG * HH);       // 131072 f32

    build_tab_kernel<<<dim3(VOCAB, 2), 256, 0, stream>>>(
        emb, W_ih_f, W_ih_b, W_hh_f, W_hh_b, tab3, whh_bf);
    lstm_rec_kernel<<<dim3(BATCH / 8, 2), 256, 0, stream>>>(x, whh_bf, tab3, hfin);
    fc_kernel<<<dim3(BATCH / 8), 256, 0, stream>>>(hfin, W_fc, b_fc, out);
}

// Round 3
// 214.406 us; speedup vs baseline: 1.2420x; 1.2420x over previous
//
#include <hip/hip_runtime.h>
#include <hip/hip_bf16.h>

// BLSTM: B=1024, T=512, V=128, H=128, HH=64, gates=256/dir.
// R19: back to the R17 structure (MB=4, 512 blocks, 2 independent barrier
// groups per CU — R18 proved the 2-block anti-phase beats in-stream ILP),
// plus the mechanical wins R18 validated and a phase-desync nudge:
//   - hbuf pitch 80 (R18: SQ_LDS_BANK_CONFLICT 2.2M -> 0)
//   - dir-reversed x staging + int4 offset reads every 4 steps (no per-step
//     dir-select/sub, 1/4 the ds_read_b32 traffic)
//   - f2bf via v_cvt_pk_bf16_f32 (RNE == the add-trick RNE; -2 VALU, -6cy
//     off the serial chain)
//   - s_setprio(1) across the latency-critical head (A-read+MFMA+gates),
//     (0) for the trans tail: head waves preempt the other block's tail ->
//     amplifies anti-phase drift between the two barrier groups.
// Math is bit-identical to R17 (same MFMA order, z4 C-in, post-MFMA x-add):
// absmax oracle must stay EXACTLY 9.766e-4.

#define T_STEPS 512
#define BATCH   1024
#define VOCAB   128
#define HID     128
#define HH      64
#define NG      256
#define MB      4      // real batch rows per block (quad-duplicated in M)
#define XPITCH  520    // 512 steps + 8 zero guard elems at the high end

#define L2E  1.4426950408889634f
#define L2E2 2.8853900817779268f

typedef __attribute__((ext_vector_type(8))) short bf16x8;
typedef __attribute__((ext_vector_type(4))) float f32x4;
typedef unsigned int  u32;
typedef unsigned short u16;

__device__ __forceinline__ float sigmoid_f(float x) {
    return __builtin_amdgcn_rcpf(1.0f + __builtin_amdgcn_exp2f(-x * L2E));
}
__device__ __forceinline__ float tanh_f(float x) {
    return 1.0f - 2.0f * __builtin_amdgcn_rcpf(1.0f + __builtin_amdgcn_exp2f(x * L2E2));
}
__device__ __forceinline__ u16 f2bf_rne(float f) {
    u32 u = __builtin_bit_cast(u32, f);
    u += 0x7FFFu + ((u >> 16) & 1u);
    return (u16)(u >> 16);
}
// barrier with LDS-only drain: global (tab) prefetch loads are NOT drained —
// their vmcnt wait lands at the use point next step.
__device__ __forceinline__ void barrier_lgkm() {
    asm volatile("s_waitcnt lgkmcnt(0)\n\ts_barrier" ::: "memory");
}

// ---------------- Kernel 1: tab build + W_hh bf16 convert (fused) ----------
// tab3 layout: [d][v][j][4] = dot(emb[v], W_ih_d[g*64+j]) for g=i,f,g,o.
__global__ __launch_bounds__(256) void build_tab_kernel(
    const float* __restrict__ emb,
    const float* __restrict__ W_ih_f,
    const float* __restrict__ W_ih_b,
    const float* __restrict__ W_hh_f,
    const float* __restrict__ W_hh_b,
    float* __restrict__ tab3,
    u16*   __restrict__ whh_bf)
{
    int v = blockIdx.x, d = blockIdx.y, tid = threadIdx.x;
    int j = tid >> 2, g = tid & 3;
    int gr = g * HH + j;                      // W_ih gate row
    const float* W = d ? W_ih_b : W_ih_f;
    const float4* e4 = (const float4*)(emb + v * HID);
    const float4* w4 = (const float4*)(W + gr * HID);
    float acc = 0.0f;
#pragma unroll
    for (int k = 0; k < HID / 4; ++k) {
        float4 e = e4[k]; float4 w = w4[k];
        acc += e.x * w.x + e.y * w.y + e.z * w.z + e.w * w.w;
    }
    tab3[(d * VOCAB + v) * NG + j * 4 + g] = acc;

    // fused W_hh convert: plain row-major [2][256][64]
    if (tid < 128) {
        const float* Whh = d ? W_hh_b : W_hh_f;
        int idx = v * 128 + tid;              // 0..16383 within this dir
        whh_bf[d * NG * HH + idx] = f2bf_rne(Whh[idx]);
    }
}

// ---------------- Kernel 2: MFMA recurrence ----------------
// grid (256,2), block 256 (4 waves), 2 blocks/CU.
__global__ __launch_bounds__(256, 2) void lstm_rec_kernel(
    const int*  __restrict__ x,        // [1024][512]
    const u16*  __restrict__ whh_bf,   // [2][256][64] bf16 bits
    const float* __restrict__ tab3,    // [2][128][64][4] floats
    float* __restrict__ hfin)          // [2][1024][64]
{
    __shared__ __align__(16) u32 xsT[MB][XPITCH];    // dir-reversed, 8320 B
    __shared__ __align__(16) u16 hbuf[2][MB][80];    // [pp][row][80], 1280 B

    const int tid  = threadIdx.x;
    const int lane = tid & 63;
    const int wave = tid >> 6;           // 0..3
    const int quad = lane >> 4;          // 0..3  == my batch row
    const int m    = lane & 15;          // my j within wave's 16
    const int dir    = blockIdx.y;
    const int b_base = blockIdx.x * MB;

    // stage x pre-scaled to tab3 byte offset (v<<10), dir-REVERSED so the
    // main loop always walks ascending for both directions.
    for (int i = tid; i < MB * T_STEPS; i += 256) {
        int bl = i >> 9, t = i & (T_STEPS - 1);
        int ts = dir ? (T_STEPS - 1 - t) : t;
        xsT[bl][ts] = ((u32)x[(b_base + bl) * T_STEPS + t]) << 10;
    }
    if (tid < MB * 8)                     // zero guards [512..519] x 4 rows
        xsT[tid >> 3][T_STEPS + (tid & 7)] = 0;
    for (int i = tid; i < (int)(sizeof(hbuf) / 4); i += 256)
        ((u32*)hbuf)[i] = 0;

    // persistent B-fragments: tile g = gate g, col m -> gate row g*64+wave*16+m
    const u16* WB = whh_bf + dir * NG * HH;
    bf16x8 Bg[4][2];
#pragma unroll
    for (int g = 0; g < 4; ++g)
#pragma unroll
        for (int kc = 0; kc < 2; ++kc)
            Bg[g][kc] = *(const bf16x8*)(WB + (g * HH + wave * 16 + m) * HH
                                            + kc * 32 + quad * 8);

    const char* tabB = (const char*)tab3 + (size_t)dir * VOCAB * NG * 4;
    const u32 joff = (u32)(wave * 16 + m) * 16u;     // j*16 bytes
    const int aoff = (m >> 2) * 80 + quad * 8;       // A-frag read (u16 units)
    const int woff = quad * 80 + wave * 16 + m;      // h write  (u16 units)

    const f32x4 z4 = {0.f, 0.f, 0.f, 0.f};           // loop-invariant C-in
    float cc = 0.f, hcur = 0.f;

    __syncthreads();   // xsT + hbuf init visible

    // x-offset quad registers: qA covers steps 8k..8k+3, qB 8k+4..8k+7.
    // Reloads land in the register whose elems are already consumed.
    int4 qA = *(const int4*)&xsT[quad][0];
    int4 qB = *(const int4*)&xsT[quad][4];
    float4 X0 = *(const float4*)(tabB + (u32)qA.x + joff);   // step-0 x-term
    float4 X1;

    auto stepf = [&](int p, const float4 Xc, float4& Xn, u32 e) {
        __builtin_amdgcn_s_setprio(1);   // latency-critical head
        const u16* rh = &hbuf[p][0][0];
        u16* wh = &hbuf[p ^ 1][0][0];
        bf16x8 Ah0 = *(const bf16x8*)(rh + aoff);         // k 0..31
        bf16x8 Ah1 = *(const bf16x8*)(rh + aoff + 32);    // k 32..63

        // issue x-term load for next step (vmcnt wait lands at next use)
        Xn = *(const float4*)(tabB + e + joff);

        // 4 gate chains, K=64 each; acc[0..3] all equal gates[quad][j]
        f32x4 aI = __builtin_amdgcn_mfma_f32_16x16x32_bf16(Ah0, Bg[0][0], z4, 0, 0, 0);
        f32x4 aF = __builtin_amdgcn_mfma_f32_16x16x32_bf16(Ah0, Bg[1][0], z4, 0, 0, 0);
        f32x4 aG = __builtin_amdgcn_mfma_f32_16x16x32_bf16(Ah0, Bg[2][0], z4, 0, 0, 0);
        f32x4 aO = __builtin_amdgcn_mfma_f32_16x16x32_bf16(Ah0, Bg[3][0], z4, 0, 0, 0);
        aI = __builtin_amdgcn_mfma_f32_16x16x32_bf16(Ah1, Bg[0][1], aI, 0, 0, 0);
        aF = __builtin_amdgcn_mfma_f32_16x16x32_bf16(Ah1, Bg[1][1], aF, 0, 0, 0);
        aG = __builtin_amdgcn_mfma_f32_16x16x32_bf16(Ah1, Bg[2][1], aG, 0, 0, 0);
        aO = __builtin_amdgcn_mfma_f32_16x16x32_bf16(Ah1, Bg[3][1], aO, 0, 0, 0);

        float gi = aI[0] + Xc.x;
        float gf = aF[0] + Xc.y;
        float gg = aG[0] + Xc.z;
        float go = aO[0] + Xc.w;
        __builtin_amdgcn_s_setprio(0);   // latency-tolerant tail

        cc   = sigmoid_f(gf) * cc + sigmoid_f(gi) * tanh_f(gg);
        hcur = sigmoid_f(go) * tanh_f(cc);

        u32 hb;   // RNE f32->bf16, single instruction (== f2bf_rne bits)
        asm("v_cvt_pk_bf16_f32 %0, %1, %2" : "=v"(hb) : "v"(hcur), "v"(hcur));
        wh[woff] = (u16)hb;

        barrier_lgkm();
    };

    for (int kk = 0; kk < T_STEPS / 8; ++kk) {
        stepf(0, X0, X1, (u32)qA.y);
        stepf(1, X1, X0, (u32)qA.z);
        stepf(0, X0, X1, (u32)qA.w);
        qA = *(const int4*)&xsT[quad][8 * kk + 8];    // steps 8kk+8..11
        stepf(1, X1, X0, (u32)qB.x);
        stepf(0, X0, X1, (u32)qB.y);
        stepf(1, X1, X0, (u32)qB.z);
        stepf(0, X0, X1, (u32)qB.w);
        qB = *(const int4*)&xsT[quad][8 * kk + 12];   // steps 8kk+12..15
        stepf(1, X1, X0, (u32)qA.x);
    }

    // every lane owns exactly one (b_base+quad, j)
    hfin[(dir * BATCH + b_base + quad) * HH + wave * 16 + m] = hcur;
}

// ---------------- Kernel 3: final FC (W_fc in LDS, 8 rows/block) ----------
__global__ __launch_bounds__(256) void fc_kernel(
    const float* __restrict__ hfin,    // [2][1024][64]
    const float* __restrict__ W_fc,    // [128][128]
    const float* __restrict__ b_fc,    // [128]
    float* __restrict__ out)           // [1024][128]
{
    __shared__ float wfc[HID * 129];   // row-padded: bank stride 129
    __shared__ float hid[8][HID];
    const int tid = threadIdx.x;
    const int b0  = blockIdx.x * 8;

    for (int i = tid; i < HID * HID; i += 256) {
        int r = i >> 7, c = i & 127;
        wfc[r * 129 + c] = W_fc[i];
    }
    for (int i = tid; i < 8 * HID; i += 256) {
        int bb = i >> 7, v = i & 127;
        hid[bb][v] = (v < HH) ? hfin[(0 * BATCH + b0 + bb) * HH + v]
                              : hfin[(1 * BATCH + b0 + bb) * HH + (v - HH)];
    }
    __syncthreads();

    const int v  = tid & 127;
    const int bs = (tid >> 7) * 4;     // rows [bs, bs+4)
    const float bias = b_fc[v];
    const float* wrow = wfc + v * 129;
#pragma unroll
    for (int r = 0; r < 4; ++r) {
        const float* h = hid[bs + r];
        float acc = bias;
#pragma unroll
        for (int k = 0; k < HID; k += 4) {
            acc += wrow[k]     * h[k]     + wrow[k + 1] * h[k + 1]
                 + wrow[k + 2] * h[k + 2] + wrow[k + 3] * h[k + 3];
        }
        out[(b0 + bs + r) * HID + v] = acc;
    }
}

extern "C" void kernel_launch(void* const* d_in, const int* in_sizes, int n_in,
                              void* d_out, int out_size, void* d_ws, size_t ws_size,
                              hipStream_t stream) {
    const int*   x      = (const int*)d_in[0];
    // d_in[1] = lengths : unused by the reference
    const float* emb    = (const float*)d_in[2];
    const float* W_ih_f = (const float*)d_in[3];
    const float* W_hh_f = (const float*)d_in[4];
    const float* W_ih_b = (const float*)d_in[5];
    const float* W_hh_b = (const float*)d_in[6];
    const float* W_fc   = (const float*)d_in[7];
    const float* b_fc   = (const float*)d_in[8];
    float* out = (float*)d_out;

    float* tab3   = (float*)d_ws;                         // 65536 f32
    u16*   whh_bf = (u16*)(tab3 + 2 * VOCAB * NG);        // 32768 u16
    float* hfin   = (float*)(whh_bf + 2 * NG * HH);       // 131072 f32

    build_tab_kernel<<<dim3(VOCAB, 2), 256, 0, stream>>>(
        emb, W_ih_f, W_ih_b, W_hh_f, W_hh_b, tab3, whh_bf);
    lstm_rec_kernel<<<dim3(BATCH / MB, 2), 256, 0, stream>>>(x, whh_bf, tab3, hfin);
    fc_kernel<<<dim3(BATCH / 8), 256, 0, stream>>>(hfin, W_fc, b_fc, out);
}